// Round 17
// baseline (36.219 us; speedup 1.0000x reference)
//
#include <hip/hip_runtime.h>

// Problem constants (B,S,D,M) = (8, 2048, 1024, 128), R = 257
#define SS 2048
#define DDIM 1024
#define D4 256          // DDIM / 4 (float4 columns)
#define BB 8
#define STRIP 8
#define NSTRIP (SS / STRIP)   // 256

typedef float f32x4 __attribute__((ext_vector_type(4)));

__device__ __forceinline__ float4 f4zero() { return make_float4(0.f, 0.f, 0.f, 0.f); }
__device__ __forceinline__ float4 f4add(float4 a, float4 b) {
    return make_float4(a.x + b.x, a.y + b.y, a.z + b.z, a.w + b.w);
}
__device__ __forceinline__ float4 f4sub(float4 a, float4 b) {
    return make_float4(a.x - b.x, a.y - b.y, a.z - b.z, a.w - b.w);
}
__device__ __forceinline__ float4 f4mul(float4 a, float4 b) {
    return make_float4(a.x * b.x, a.y * b.y, a.z * b.z, a.w * b.w);
}
__device__ __forceinline__ float4 f4fma(float4 a, float4 b, float4 c) {
    return make_float4(fmaf(a.x, b.x, c.x), fmaf(a.y, b.y, c.y),
                       fmaf(a.z, b.z, c.z), fmaf(a.w, b.w, c.w));
}
__device__ __forceinline__ float4 f4fmas(float s, float4 b, float4 c) {
    return make_float4(fmaf(s, b.x, c.x), fmaf(s, b.y, c.y),
                       fmaf(s, b.z, c.z), fmaf(s, b.w, c.w));
}
__device__ __forceinline__ float4 f4scale(float4 a, float s) {
    return make_float4(a.x * s, a.y * s, a.z * s, a.w * s);
}
__device__ __forceinline__ float4 f4adds(float4 a, float s) {
    return make_float4(a.x + s, a.y + s, a.z + s, a.w + s);
}
__device__ __forceinline__ void nt_store(float4* p, float4 v) {
    __builtin_nontemporal_store(*(f32x4*)&v, (f32x4*)p);   // out never re-read (r11: win)
}
__device__ __forceinline__ float4 nt_load(const float4* p) {
    f32x4 v = __builtin_nontemporal_load((const f32x4*)p); // read-once rows only
    return *(float4*)&v;
}
// Full-NT loads refuted (r12: +4.5 us — halo rows need L2). THIS round: NT
// only on the 6-of-10 rows per strip that are globally read-once.

// Extras layout in ws after pre[256][D4] (all float4[D4] rows):
//  0:K0  1:Kc  2:W0  3:W1s  4:W2  5:E0(K0e)  6:EA(w0*Tmm)  7:EB(w2*Tmp)

// ---------------------------------------------------------------------------
// k_pre_lds: Pre[r][d] = sum_{r'=1..r} table[r'][d]  (64 blocks x 256 thr,
// 4-row register chunks + 6-step Hillis-Steele; max dep-load chain = 4).
// Epilogue: 4 threads/block compute all per-d constants once (r16).
// ---------------------------------------------------------------------------
__global__ __launch_bounds__(256) void k_pre_lds(const float4* __restrict__ tbl4,
                                                 const float4* __restrict__ bias4,
                                                 const float* __restrict__ w,
                                                 float4* __restrict__ pre,
                                                 float4* __restrict__ ex) {
    __shared__ float4 buf[2][64][4];    // 8 KB ping-pong
    __shared__ float4 pf[4];            // Pre[255] per col-in-block
    const int t = threadIdx.x;
    const int k = t >> 2;               // chunk 0..63
    const int j = t & 3;                // col-within-block
    const int col = (blockIdx.x << 2) + j;   // 0..255

    const float4 p1 = tbl4[(4 * k + 1) * D4 + col];
    const float4 p2 = f4add(p1, tbl4[(4 * k + 2) * D4 + col]);
    const float4 p3 = f4add(p2, tbl4[(4 * k + 3) * D4 + col]);
    const float4 p4 = f4add(p3, tbl4[(4 * k + 4) * D4 + col]);

    buf[0][k][j] = p4;
    __syncthreads();
    int pb = 0;
#pragma unroll
    for (int s = 1; s < 64; s <<= 1) {
        float4 v = buf[pb][k][j];
        if (k >= s) v = f4add(v, buf[pb][k - s][j]);
        buf[pb ^ 1][k][j] = v;
        pb ^= 1;
        __syncthreads();
    }
    const float4 base = f4sub(buf[pb][k][j], p4);   // exclusive: rows 1..4k

    if (k == 0) pre[col] = f4zero();                 // Pre[0] = 0
    pre[(4 * k + 1) * D4 + col] = f4add(base, p1);
    pre[(4 * k + 2) * D4 + col] = f4add(base, p2);
    pre[(4 * k + 3) * D4 + col] = f4add(base, p3);
    if (k < 63) pre[(4 * k + 4) * D4 + col] = f4add(base, p4);  // row 256 unused
    if (k == 63) pf[j] = f4add(base, p3);            // Pre[255] = rows 1..255
    __syncthreads();

    if (k == 0) {
        // per-column constant factory (4 threads/block; 9 indep loads each)
        const float4 PF  = pf[j];
        const float4 T0  = tbl4[0 * D4 + col];
        const float4 T2M = tbl4[256 * D4 + col];
        const float4 Tm  = tbl4[128 * D4 + col];
        const float4 Tmm = tbl4[127 * D4 + col];
        const float4 Tmp = tbl4[129 * D4 + col];
        const float4 bs  = bias4[col];
        const float4* w4 = (const float4*)w;      // (D,3) row-major
        const float4 q0 = w4[3 * col + 0];
        const float4 q1 = w4[3 * col + 1];
        const float4 q2 = w4[3 * col + 2];
        const float4 W0 = make_float4(q0.x, q0.w, q1.z, q2.y);
        const float4 W1 = make_float4(q0.y, q1.x, q1.w, q2.z);
        const float4 W2 = make_float4(q0.z, q1.y, q2.x, q2.w);

        const float4 E0 = f4fma(f4adds(W1, -1.f), Tm, bs);   // bias + (w1-1)Tm
        const float4 EA = f4mul(W0, Tmm);
        const float4 EB = f4mul(W2, Tmp);
        float4 K0 = f4add(E0, f4add(EA, EB));
        K0 = f4fmas(1920.f, T0, K0);
        K0 = f4fmas(-127.f, T2M, K0);
        K0 = f4add(K0, PF);

        ex[0 * D4 + col] = K0;
        ex[1 * D4 + col] = f4sub(T2M, T0);        // Kc
        ex[2 * D4 + col] = W0;
        ex[3 * D4 + col] = f4adds(W1, (float)(SS - 1));   // W1s
        ex[4 * D4 + col] = W2;
        ex[5 * D4 + col] = E0;
        ex[6 * D4 + col] = EA;
        ex[7 * D4 + col] = EB;
    }
}

// ---------------------------------------------------------------------------
// k_main: out[b,i,d] = (W0*x[b,i-1] + W1s*x[b,i] + W2*x[b,i+1] + pos(i,d)) / S
// Interior i in [128,1919]: pos = K0 + i*Kc (hoisted in ws).
// Proven: STRIP=8, rolling regs, plain __launch_bounds__(256), NT stores,
// XCD batch-per-XCD swizzle. THIS ROUND: selective NT loads — rows
// i0+1..i0+6 (read exactly once globally) bypass L2; the 4 halo-shared rows
// (i0-1, i0, i0+7, i0+8) stay cached on BOTH reader sides, so strip-halo
// reuse still hits L2 while stream allocation drops ~2.5x.
// ---------------------------------------------------------------------------
__global__ __launch_bounds__(256) void k_main(const float4* __restrict__ x4,
                                              const float4* __restrict__ tbl4,
                                              const float4* __restrict__ pre4,
                                              const float4* __restrict__ ex,
                                              float4* __restrict__ out4) {
    const int tid = threadIdx.x;          // d4
    // XCD-chunked bijective swizzle (grid 2048): XCD k gets batch k exactly.
    const int bid = ((blockIdx.x & 7) << 8) | (blockIdx.x >> 3);
    const int strip = bid & (NSTRIP - 1);
    const int b = bid >> 8;               // log2(NSTRIP) = 8
    const int i0 = strip * STRIP;
    const float invS = 1.0f / (float)SS;

    const float4* xr = x4 + (b * SS + i0) * D4 + tid;
    float4* orow = out4 + (b * SS + i0) * D4 + tid;

    if (strip >= 16 && strip <= 239) {
        // ------- interior path: i in [128, 1919] -------
        const float4 K0  = ex[0 * D4 + tid];
        const float4 Kc  = ex[1 * D4 + tid];
        const float4 W0  = ex[2 * D4 + tid];
        const float4 W1s = ex[3 * D4 + tid];
        const float4 W2  = ex[4 * D4 + tid];

        float4 xm = xr[-D4];        // halo-shared: cached
        float4 x0 = xr[0];          // halo-shared: cached
#pragma unroll
        for (int j = 0; j < STRIP; ++j) {
            // rows i0+1..i0+6 read-once -> NT; i0+7, i0+8 halo-shared -> cached
            const float4 xp = (j < 6) ? nt_load(&xr[(j + 1) * D4])
                                      : xr[(j + 1) * D4];
            const float fi = (float)(i0 + j);
            float4 acc = f4fmas(fi, Kc, K0);
            acc = f4fma(W0, xm, acc);
            acc = f4fma(W1s, x0, acc);
            acc = f4fma(W2, xp, acc);
            nt_store(&orow[j * D4], f4scale(acc, invS));
            xm = x0; x0 = xp;
        }
    } else {
        // ------- edge path: general formula, per-i Pre lookups (L2-hot) -------
        const float4 W0  = ex[2 * D4 + tid];
        const float4 W1s = ex[3 * D4 + tid];
        const float4 W2  = ex[4 * D4 + tid];
        const float4 E0  = ex[5 * D4 + tid];
        const float4 EA  = ex[6 * D4 + tid];
        const float4 EB  = ex[7 * D4 + tid];
        const float4 T0  = tbl4[0 * D4 + tid];
        const float4 T2M = tbl4[256 * D4 + tid];

        float4 xm = (i0 == 0) ? f4zero() : xr[-D4];
        float4 x0 = xr[0];
#pragma unroll
        for (int j = 0; j < STRIP; ++j) {
            const int i = i0 + j;
            const float4 xp = (i < SS - 1) ? xr[(j + 1) * D4] : f4zero();
            const int cl = max(0, 1920 - i);          // clipped -M count (T[0])
            const int ch = max(0, i - 127);           // clipped +M count (T[2M])
            const int hi = min(i + 128, 255);
            const int lom1 = max(i - 1920, 0);        // lo - 1
            const float4 ph = pre4[hi * D4 + tid];
            const float4 pl = pre4[lom1 * D4 + tid];
            float4 pos = f4add(E0, f4sub(ph, pl));
            pos = f4fmas((float)cl, T0, pos);
            pos = f4fmas((float)ch, T2M, pos);
            if (i >= 1)      pos = f4add(pos, EA);
            if (i <= SS - 2) pos = f4add(pos, EB);
            float4 acc = f4fma(W0, xm, pos);
            acc = f4fma(W1s, x0, acc);
            acc = f4fma(W2, xp, acc);
            nt_store(&orow[j * D4], f4scale(acc, invS));
            xm = x0; x0 = xp;
        }
    }
}

extern "C" void kernel_launch(void* const* d_in, const int* in_sizes, int n_in,
                              void* d_out, int out_size, void* d_ws, size_t ws_size,
                              hipStream_t stream) {
    const float* x     = (const float*)d_in[0];   // (B,S,D)
    const float* table = (const float*)d_in[1];   // (R,D) = (257,1024)
    const float* w     = (const float*)d_in[2];   // (D,3)
    const float* bias  = (const float*)d_in[3];   // (D,)
    float* out = (float*)d_out;

    // ws: pre[256][1024] floats (1 MiB) + extras[8][1024] floats (32 KB)
    float* pre = (float*)d_ws;
    float* ex  = pre + 256 * DDIM;

    k_pre_lds<<<64, 256, 0, stream>>>((const float4*)table,
                                      (const float4*)bias, w,
                                      (float4*)pre, (float4*)ex);
    k_main<<<BB * NSTRIP, 256, 0, stream>>>((const float4*)x,
                                            (const float4*)table,
                                            (const float4*)pre,
                                            (const float4*)ex,
                                            (float4*)out);
}

// Round 18
// 31.180 us; speedup vs baseline: 1.1616x; 1.1616x over previous
//
#include <hip/hip_runtime.h>

// Problem constants (B,S,D,M) = (8, 2048, 1024, 128), R = 257
#define SS 2048
#define DDIM 1024
#define D4 256          // DDIM / 4 (float4 columns)
#define BB 8
#define STRIP 8
#define NSTRIP (SS / STRIP)   // 256

typedef float f32x4 __attribute__((ext_vector_type(4)));

__device__ __forceinline__ float4 f4zero() { return make_float4(0.f, 0.f, 0.f, 0.f); }
__device__ __forceinline__ float4 f4add(float4 a, float4 b) {
    return make_float4(a.x + b.x, a.y + b.y, a.z + b.z, a.w + b.w);
}
__device__ __forceinline__ float4 f4sub(float4 a, float4 b) {
    return make_float4(a.x - b.x, a.y - b.y, a.z - b.z, a.w - b.w);
}
__device__ __forceinline__ float4 f4mul(float4 a, float4 b) {
    return make_float4(a.x * b.x, a.y * b.y, a.z * b.z, a.w * b.w);
}
__device__ __forceinline__ float4 f4fma(float4 a, float4 b, float4 c) {
    return make_float4(fmaf(a.x, b.x, c.x), fmaf(a.y, b.y, c.y),
                       fmaf(a.z, b.z, c.z), fmaf(a.w, b.w, c.w));
}
__device__ __forceinline__ float4 f4fmas(float s, float4 b, float4 c) {
    return make_float4(fmaf(s, b.x, c.x), fmaf(s, b.y, c.y),
                       fmaf(s, b.z, c.z), fmaf(s, b.w, c.w));
}
__device__ __forceinline__ float4 f4scale(float4 a, float s) {
    return make_float4(a.x * s, a.y * s, a.z * s, a.w * s);
}
__device__ __forceinline__ float4 f4adds(float4 a, float s) {
    return make_float4(a.x + s, a.y + s, a.z + s, a.w + s);
}
__device__ __forceinline__ void nt_store(float4* p, float4 v) {
    __builtin_nontemporal_store(*(f32x4*)&v, (f32x4*)p);   // out never re-read (r11: win)
}
// NT LOADS: categorically refuted — full (r12: +4.5us) AND selective
// read-once-only (r17: +4.9us). The gfx950 NT-load path is slower
// regardless of reuse. Loads stay plain/cached.

// Extras layout in ws after pre[256][D4] (all float4[D4] rows):
//  0:K0  1:Kc  2:W0  3:W1s  4:W2  5:E0(K0e)  6:EA(w0*Tmm)  7:EB(w2*Tmp)

// ---------------------------------------------------------------------------
// k_pre_lds: Pre[r][d] = sum_{r'=1..r} table[r'][d]  (64 blocks x 256 thr,
// 4-row register chunks + 6-step Hillis-Steele; max dep-load chain = 4 —
// deep chains in setup kernels cost 7-14us: r5/r7 lessons).
// Epilogue: 4 threads/block compute all per-d constants once (r16, neutral
// but simplifies k_main).
// ---------------------------------------------------------------------------
__global__ __launch_bounds__(256) void k_pre_lds(const float4* __restrict__ tbl4,
                                                 const float4* __restrict__ bias4,
                                                 const float* __restrict__ w,
                                                 float4* __restrict__ pre,
                                                 float4* __restrict__ ex) {
    __shared__ float4 buf[2][64][4];    // 8 KB ping-pong
    __shared__ float4 pf[4];            // Pre[255] per col-in-block
    const int t = threadIdx.x;
    const int k = t >> 2;               // chunk 0..63
    const int j = t & 3;                // col-within-block
    const int col = (blockIdx.x << 2) + j;   // 0..255

    const float4 p1 = tbl4[(4 * k + 1) * D4 + col];
    const float4 p2 = f4add(p1, tbl4[(4 * k + 2) * D4 + col]);
    const float4 p3 = f4add(p2, tbl4[(4 * k + 3) * D4 + col]);
    const float4 p4 = f4add(p3, tbl4[(4 * k + 4) * D4 + col]);

    buf[0][k][j] = p4;
    __syncthreads();
    int pb = 0;
#pragma unroll
    for (int s = 1; s < 64; s <<= 1) {
        float4 v = buf[pb][k][j];
        if (k >= s) v = f4add(v, buf[pb][k - s][j]);
        buf[pb ^ 1][k][j] = v;
        pb ^= 1;
        __syncthreads();
    }
    const float4 base = f4sub(buf[pb][k][j], p4);   // exclusive: rows 1..4k

    if (k == 0) pre[col] = f4zero();                 // Pre[0] = 0
    pre[(4 * k + 1) * D4 + col] = f4add(base, p1);
    pre[(4 * k + 2) * D4 + col] = f4add(base, p2);
    pre[(4 * k + 3) * D4 + col] = f4add(base, p3);
    if (k < 63) pre[(4 * k + 4) * D4 + col] = f4add(base, p4);  // row 256 unused
    if (k == 63) pf[j] = f4add(base, p3);            // Pre[255] = rows 1..255
    __syncthreads();

    if (k == 0) {
        // per-column constant factory (4 threads/block; 9 indep loads each)
        const float4 PF  = pf[j];
        const float4 T0  = tbl4[0 * D4 + col];
        const float4 T2M = tbl4[256 * D4 + col];
        const float4 Tm  = tbl4[128 * D4 + col];
        const float4 Tmm = tbl4[127 * D4 + col];
        const float4 Tmp = tbl4[129 * D4 + col];
        const float4 bs  = bias4[col];
        const float4* w4 = (const float4*)w;      // (D,3) row-major
        const float4 q0 = w4[3 * col + 0];
        const float4 q1 = w4[3 * col + 1];
        const float4 q2 = w4[3 * col + 2];
        const float4 W0 = make_float4(q0.x, q0.w, q1.z, q2.y);
        const float4 W1 = make_float4(q0.y, q1.x, q1.w, q2.z);
        const float4 W2 = make_float4(q0.z, q1.y, q2.x, q2.w);

        const float4 E0 = f4fma(f4adds(W1, -1.f), Tm, bs);   // bias + (w1-1)Tm
        const float4 EA = f4mul(W0, Tmm);
        const float4 EB = f4mul(W2, Tmp);
        float4 K0 = f4add(E0, f4add(EA, EB));
        K0 = f4fmas(1920.f, T0, K0);
        K0 = f4fmas(-127.f, T2M, K0);
        K0 = f4add(K0, PF);

        ex[0 * D4 + col] = K0;
        ex[1 * D4 + col] = f4sub(T2M, T0);        // Kc
        ex[2 * D4 + col] = W0;
        ex[3 * D4 + col] = f4adds(W1, (float)(SS - 1));   // W1s
        ex[4 * D4 + col] = W2;
        ex[5 * D4 + col] = E0;
        ex[6 * D4 + col] = EA;
        ex[7 * D4 + col] = EB;
    }
}

// ---------------------------------------------------------------------------
// k_main: out[b,i,d] = (W0*x[b,i-1] + W1s*x[b,i] + W2*x[b,i+1] + pos(i,d)) / S
// Interior i in [128,1919]: pos = K0 + i*Kc (hoisted in ws).
// Best-measured config (r13/r16 = 31.0-31.3us): STRIP=8 (r14: 16 worse),
// rolling regs (r15: batching worse), plain __launch_bounds__(256) (r9:
// min-waves arg -> 45MB spill), NT stores (r11: win), plain cached loads
// (r12/r17: any NT on loads is +4.5-5us), XCD batch-per-XCD swizzle (r13).
// ---------------------------------------------------------------------------
__global__ __launch_bounds__(256) void k_main(const float4* __restrict__ x4,
                                              const float4* __restrict__ tbl4,
                                              const float4* __restrict__ pre4,
                                              const float4* __restrict__ ex,
                                              float4* __restrict__ out4) {
    const int tid = threadIdx.x;          // d4
    // XCD-chunked bijective swizzle (grid 2048): XCD k gets batch k exactly.
    const int bid = ((blockIdx.x & 7) << 8) | (blockIdx.x >> 3);
    const int strip = bid & (NSTRIP - 1);
    const int b = bid >> 8;               // log2(NSTRIP) = 8
    const int i0 = strip * STRIP;
    const float invS = 1.0f / (float)SS;

    const float4* xr = x4 + (b * SS + i0) * D4 + tid;
    float4* orow = out4 + (b * SS + i0) * D4 + tid;

    if (strip >= 16 && strip <= 239) {
        // ------- interior path: i in [128, 1919] -------
        const float4 K0  = ex[0 * D4 + tid];
        const float4 Kc  = ex[1 * D4 + tid];
        const float4 W0  = ex[2 * D4 + tid];
        const float4 W1s = ex[3 * D4 + tid];
        const float4 W2  = ex[4 * D4 + tid];

        float4 xm = xr[-D4];        // i0-1 >= 127: safe
        float4 x0 = xr[0];
#pragma unroll
        for (int j = 0; j < STRIP; ++j) {
            const float4 xp = xr[(j + 1) * D4];   // i0+STRIP <= 1920: safe
            const float fi = (float)(i0 + j);
            float4 acc = f4fmas(fi, Kc, K0);
            acc = f4fma(W0, xm, acc);
            acc = f4fma(W1s, x0, acc);
            acc = f4fma(W2, xp, acc);
            nt_store(&orow[j * D4], f4scale(acc, invS));
            xm = x0; x0 = xp;
        }
    } else {
        // ------- edge path: general formula, per-i Pre lookups (L2-hot) -------
        const float4 W0  = ex[2 * D4 + tid];
        const float4 W1s = ex[3 * D4 + tid];
        const float4 W2  = ex[4 * D4 + tid];
        const float4 E0  = ex[5 * D4 + tid];
        const float4 EA  = ex[6 * D4 + tid];
        const float4 EB  = ex[7 * D4 + tid];
        const float4 T0  = tbl4[0 * D4 + tid];
        const float4 T2M = tbl4[256 * D4 + tid];

        float4 xm = (i0 == 0) ? f4zero() : xr[-D4];
        float4 x0 = xr[0];
#pragma unroll
        for (int j = 0; j < STRIP; ++j) {
            const int i = i0 + j;
            const float4 xp = (i < SS - 1) ? xr[(j + 1) * D4] : f4zero();
            const int cl = max(0, 1920 - i);          // clipped -M count (T[0])
            const int ch = max(0, i - 127);           // clipped +M count (T[2M])
            const int hi = min(i + 128, 255);
            const int lom1 = max(i - 1920, 0);        // lo - 1
            const float4 ph = pre4[hi * D4 + tid];
            const float4 pl = pre4[lom1 * D4 + tid];
            float4 pos = f4add(E0, f4sub(ph, pl));
            pos = f4fmas((float)cl, T0, pos);
            pos = f4fmas((float)ch, T2M, pos);
            if (i >= 1)      pos = f4add(pos, EA);
            if (i <= SS - 2) pos = f4add(pos, EB);
            float4 acc = f4fma(W0, xm, pos);
            acc = f4fma(W1s, x0, acc);
            acc = f4fma(W2, xp, acc);
            nt_store(&orow[j * D4], f4scale(acc, invS));
            xm = x0; x0 = xp;
        }
    }
}

extern "C" void kernel_launch(void* const* d_in, const int* in_sizes, int n_in,
                              void* d_out, int out_size, void* d_ws, size_t ws_size,
                              hipStream_t stream) {
    const float* x     = (const float*)d_in[0];   // (B,S,D)
    const float* table = (const float*)d_in[1];   // (R,D) = (257,1024)
    const float* w     = (const float*)d_in[2];   // (D,3)
    const float* bias  = (const float*)d_in[3];   // (D,)
    float* out = (float*)d_out;

    // ws: pre[256][1024] floats (1 MiB) + extras[8][1024] floats (32 KB)
    float* pre = (float*)d_ws;
    float* ex  = pre + 256 * DDIM;

    k_pre_lds<<<64, 256, 0, stream>>>((const float4*)table,
                                      (const float4*)bias, w,
                                      (float4*)pre, (float4*)ex);
    k_main<<<BB * NSTRIP, 256, 0, stream>>>((const float4*)x,
                                            (const float4*)table,
                                            (const float4*)pre,
                                            (const float4*)ex,
                                            (float4*)out);
}